// Round 1
// baseline (269.459 us; speedup 1.0000x reference)
//
#include <hip/hip_runtime.h>
#include <math.h>

// x: (B=64, C=3, H=512, W=512) fp32.  out: (64, 18) fp32.
// For each 8x8 block: |FFT2|[u,v] at bands (0,1),(1,0),(1,1),(2,2),(3,3),(4,4),
// mean over the 64x64 block grid of each (b,c) image.
//
// One thread = one 8x8 block. Workgroup of 256 = 4 block-rows x 64 block-cols.
// Grid = B*C*16. Per-wave shuffle reduce -> LDS across 4 waves -> atomicAdd.

#define IMG_H 512
#define IMG_W 512

__global__ __launch_bounds__(256) void dct_band_kernel(const float* __restrict__ x,
                                                       float* __restrict__ out) {
    const int wg   = blockIdx.x;
    const int img  = wg >> 4;          // b*3 + c   (0..191)
    const int rg   = wg & 15;          // row-group: 4 block-rows each
    const int t    = threadIdx.x;
    const int brow = rg * 4 + (t >> 6); // 0..63
    const int bcol = t & 63;            // 0..63

    const float* p = x + (size_t)img * (IMG_H * IMG_W)
                       + (size_t)(brow * 8) * IMG_W + bcol * 8;

    const float C1 = 0.70710678118654752440f;
    // twiddle tables: e^{-2*pi*i*k/8} = ct[k] - i*st[k]
    const float ct[8] = {1.f,  C1, 0.f, -C1, -1.f, -C1, 0.f,  C1};
    const float st[8] = {0.f,  C1, 1.f,  C1,  0.f, -C1, -1.f, -C1};

    float F01r = 0.f, F01i = 0.f;   // (u=0, v=1)
    float F10r = 0.f, F10i = 0.f;   // (u=1, v=0)
    float F11r = 0.f, F11i = 0.f;   // (u=1, v=1)
    float F22r = 0.f, F22i = 0.f;   // (u=2, v=2)
    float F33r = 0.f, F33i = 0.f;   // (u=3, v=3)
    float F44  = 0.f;               // (u=4, v=4) purely real

#pragma unroll
    for (int i = 0; i < 8; ++i) {
        const float4 a = *(const float4*)(p + (size_t)i * IMG_W);
        const float4 b = *(const float4*)(p + (size_t)i * IMG_W + 4);
        const float x0 = a.x, x1 = a.y, x2 = a.z, x3 = a.w;
        const float x4 = b.x, x5 = b.y, x6 = b.z, x7 = b.w;

        // Row DFT G_i[v] = sum_j x_j e^{-2*pi*i*v*j/8}, for v in {0,1,2,3,4}
        const float g0  = x0 + x1 + x2 + x3 + x4 + x5 + x6 + x7;               // v=0 (real)
        const float g1r = x0 - x4 + C1 * (x1 - x3 - x5 + x7);                  // v=1
        const float g1i = -(C1 * (x1 + x3 - x5 - x7) + x2 - x6);
        const float g2r = x0 - x2 + x4 - x6;                                   // v=2
        const float g2i = -(x1 - x3 + x5 - x7);
        const float g3r = x0 - x4 + C1 * (-x1 + x3 + x5 - x7);                 // v=3
        const float g3i = -(C1 * (x1 + x3 - x5 - x7) - x2 + x6);
        const float g4  = x0 - x1 + x2 - x3 + x4 - x5 + x6 - x7;               // v=4 (real)

        // Column twiddles e^{-2*pi*i*u*i/8} (compile-time folded: i is unrolled)
        const float c1 = ct[i],           s1 = st[i];
        const float c2 = ct[(2 * i) & 7], s2 = st[(2 * i) & 7];
        const float c3 = ct[(3 * i) & 7], s3 = st[(3 * i) & 7];

        // (gr + i*gi) * (c - i*s) = (gr*c + gi*s) + i*(gi*c - gr*s)
        F01r += g1r;             F01i += g1i;
        F10r += g0 * c1;         F10i -= g0 * s1;
        F11r += g1r * c1 + g1i * s1;   F11i += g1i * c1 - g1r * s1;
        F22r += g2r * c2 + g2i * s2;   F22i += g2i * c2 - g2r * s2;
        F33r += g3r * c3 + g3i * s3;   F33i += g3i * c3 - g3r * s3;
        F44  += (i & 1) ? -g4 : g4;
    }

    float m[6];
    m[0] = sqrtf(F01r * F01r + F01i * F01i);
    m[1] = sqrtf(F10r * F10r + F10i * F10i);
    m[2] = sqrtf(F11r * F11r + F11i * F11i);
    m[3] = sqrtf(F22r * F22r + F22i * F22i);
    m[4] = sqrtf(F33r * F33r + F33i * F33i);
    m[5] = fabsf(F44);

    // wave(64)-level reduce of the 6 magnitudes
#pragma unroll
    for (int off = 32; off > 0; off >>= 1) {
#pragma unroll
        for (int k = 0; k < 6; ++k) m[k] += __shfl_down(m[k], off);
    }

    __shared__ float red[4][6];
    const int wave = t >> 6;
    if ((t & 63) == 0) {
#pragma unroll
        for (int k = 0; k < 6; ++k) red[wave][k] = m[k];
    }
    __syncthreads();

    if (t < 6) {
        const float s = red[0][t] + red[1][t] + red[2][t] + red[3][t];
        atomicAdd(&out[img * 6 + t], s * (1.0f / 4096.0f));
    }
}

extern "C" void kernel_launch(void* const* d_in, const int* in_sizes, int n_in,
                              void* d_out, int out_size, void* d_ws, size_t ws_size,
                              hipStream_t stream) {
    const float* x = (const float*)d_in[0];
    float* out = (float*)d_out;

    // d_out is poisoned 0xAA before every call — zero it for the atomics.
    hipMemsetAsync(d_out, 0, (size_t)out_size * sizeof(float), stream);

    const int n_imgs = 64 * 3;
    dim3 grid(n_imgs * 16);   // 16 row-groups of 4 block-rows per image
    dim3 block(256);
    dct_band_kernel<<<grid, block, 0, stream>>>(x, out);
}